// Round 4
// baseline (390.781 us; speedup 1.0000x reference)
//
#include <hip/hip_runtime.h>
#include <hip/hip_fp16.h>

// DGConv: K=2 diffusion steps of x <- (1-d)x + d * (D^-1/2 (A+I) D^-1/2) x, then x @ W + b.
// N=100000 nodes, E=1600000 edges, D=64 features. delta = 5.27/2 = 2.635.
//
// Key trick: pre-scale z = dinv (.) x in fp16. Then
//   sum_e w_e x[src] = dinv[dst] * sum_e z[src],  self-loop = dinv^2 * x.
// Gather rows are fp16 (128B = ONE cache line per gather) and carry no weights.

#define TPB 256
#define SCAN_T 256
#define SCAN_I 4
#define SCAN_CHUNK (SCAN_T * SCAN_I)   // 1024 elements per scan block
#define BATCH 16

__global__ void count_kernel(const int* __restrict__ dst, int* __restrict__ counts, int e) {
    int i = blockIdx.x * blockDim.x + threadIdx.x;
    if (i < e) atomicAdd(&counts[dst[i]], 1);
}

// Pass 1: per-block sums of counts.
__global__ void scan_partials(const int* __restrict__ counts, int* __restrict__ bsums, int n) {
    __shared__ int red[SCAN_T];
    int t = threadIdx.x;
    int base = blockIdx.x * SCAN_CHUNK + t * SCAN_I;
    int s = 0;
#pragma unroll
    for (int k = 0; k < SCAN_I; ++k) { int i = base + k; if (i < n) s += counts[i]; }
    red[t] = s;
    __syncthreads();
    for (int off = SCAN_T / 2; off > 0; off >>= 1) {
        if (t < off) red[t] += red[t + off];
        __syncthreads();
    }
    if (t == 0) bsums[blockIdx.x] = red[0];
}

// Pass 2: exclusive scan of the (<=512) block sums, single block. Also sets row_ptr[n]=e.
__global__ void scan_bsums(int* __restrict__ bsums, int nb, int* __restrict__ row_ptr,
                           int n, int e) {
    __shared__ int s[512];
    int t = threadIdx.x;
    int v = (t < nb) ? bsums[t] : 0;
    s[t] = v;
    __syncthreads();
    for (int off = 1; off < 512; off <<= 1) {
        int a = (t >= off) ? s[t - off] : 0;
        __syncthreads();
        s[t] += a;
        __syncthreads();
    }
    if (t < nb) bsums[t] = s[t] - v;   // exclusive prefix
    if (t == 0) row_ptr[n] = e;
}

// Pass 3: per-block rescan + emit row_ptr/cursor/dinv.
__global__ void scan_emit(const int* __restrict__ counts, const int* __restrict__ boffs,
                          int* __restrict__ row_ptr, int* __restrict__ cursor,
                          float* __restrict__ dinv, int n) {
    __shared__ int red[SCAN_T];
    int t = threadIdx.x;
    int base = blockIdx.x * SCAN_CHUNK + t * SCAN_I;
    int c[SCAN_I];
    int s = 0;
#pragma unroll
    for (int k = 0; k < SCAN_I; ++k) { int i = base + k; c[k] = (i < n) ? counts[i] : 0; s += c[k]; }
    red[t] = s;
    __syncthreads();
    for (int off = 1; off < SCAN_T; off <<= 1) {      // inclusive Hillis-Steele
        int a = (t >= off) ? red[t - off] : 0;
        __syncthreads();
        red[t] += a;
        __syncthreads();
    }
    int run = boffs[blockIdx.x] + red[t] - s;          // exclusive prefix for this thread
#pragma unroll
    for (int k = 0; k < SCAN_I; ++k) {
        int i = base + k;
        if (i < n) {
            row_ptr[i] = run;
            cursor[i]  = run;
            dinv[i] = rsqrtf((float)(c[k] + 1));       // +1 self-loop; always > 0
            run += c[k];
        }
    }
}

// zh[i][f] = fp16(dinv[i] * x[i][f]); also zero row n of zh AND z1h (tail-clamp target).
__global__ void cast_z(const float* __restrict__ x, const float* __restrict__ dinv,
                       __half* __restrict__ zh, __half* __restrict__ z1h, int n) {
    int i = blockIdx.x * blockDim.x + threadIdx.x;
    int total = n * 64;
    if (i < total) {
        zh[i] = __float2half(dinv[i >> 6] * x[i]);
    } else if (i < total + 64) {
        zh[i]  = __float2half(0.f);
        z1h[i] = __float2half(0.f);
    }
}

// Pure column scatter: weights are folded into z, so no dinv gathers here.
__global__ void fill_kernel(const int* __restrict__ src, const int* __restrict__ dst,
                            int* __restrict__ cursor, int* __restrict__ col, int e) {
    int i = blockIdx.x * blockDim.x + threadIdx.x;
    if (i >= e) return;
    int pos = atomicAdd(&cursor[dst[i]], 1);
    col[pos] = src[i];
}

// Batch-16 pipelined gather of fp16 rows: 16 col loads -> 16 one-line row gathers -> adds.
// Tail lanes clamp to the all-zero row `nzero` (L1-resident after first touch).
__device__ __forceinline__ float spmm_row(const __half* __restrict__ zh,
                                          const int* __restrict__ col,
                                          int beg, int end, int lane, int nzero) {
    float acc = 0.f;
    for (int j = beg; j < end; j += BATCH) {
        int c[BATCH];
#pragma unroll
        for (int k = 0; k < BATCH; ++k) {
            int jj = j + k;
            int cc = col[min(jj, end - 1)];            // unconditional in-bounds load
            c[k] = (jj < end) ? cc : nzero;
        }
        float xv[BATCH];
#pragma unroll
        for (int k = 0; k < BATCH; ++k)
            xv[k] = __half2float(zh[(unsigned)c[k] * 64u + (unsigned)lane]);
#pragma unroll
        for (int k = 0; k < BATCH; ++k) acc += xv[k];
    }
    return acc;
}

// Step 1: x (f32) + zh -> x1h (state) and z1h (= dinv*x1, for step-2 gathers).
__global__ void spmm1_kernel(const float* __restrict__ x, const __half* __restrict__ zh,
                             __half* __restrict__ x1h, __half* __restrict__ z1h,
                             const int* __restrict__ row_ptr, const int* __restrict__ col,
                             const float* __restrict__ dinv, int n, float delta) {
    int node = blockIdx.x * (blockDim.x >> 6) + (threadIdx.x >> 6);
    int lane = threadIdx.x & 63;
    if (node >= n) return;
    unsigned idx = (unsigned)node * 64u + (unsigned)lane;
    float xi = x[idx];
    float dv = dinv[node];
    float acc = spmm_row(zh, col, row_ptr[node], row_ptr[node + 1], lane, n);
    float x1 = (1.f - delta) * xi + delta * dv * (dv * xi + acc);
    x1h[idx] = __float2half(x1);
    z1h[idx] = __float2half(dv * x1);
}

// Step 2 SpMM fused with y = x2 @ W + b (shfl-broadcast row, W staged in LDS).
__global__ void spmm2_gemm_kernel(const __half* __restrict__ x1h, const __half* __restrict__ z1h,
                                  float* __restrict__ y,
                                  const int* __restrict__ row_ptr, const int* __restrict__ col,
                                  const float* __restrict__ dinv,
                                  const float* __restrict__ W, const float* __restrict__ b,
                                  int n, float delta) {
    __shared__ float Ws[64 * 64];
    __shared__ float bs[64];
    for (int i = threadIdx.x; i < 64 * 64; i += blockDim.x) Ws[i] = W[i];
    if (threadIdx.x < 64) bs[threadIdx.x] = b[threadIdx.x];
    __syncthreads();
    int node = blockIdx.x * (blockDim.x >> 6) + (threadIdx.x >> 6);
    int lane = threadIdx.x & 63;
    if (node >= n) return;
    unsigned idx = (unsigned)node * 64u + (unsigned)lane;
    float xi = __half2float(x1h[idx]);
    float dv = dinv[node];
    float acc = spmm_row(z1h, col, row_ptr[node], row_ptr[node + 1], lane, n);
    float res = (1.f - delta) * xi + delta * dv * (dv * xi + acc);
    float o = bs[lane];
#pragma unroll
    for (int k = 0; k < 64; ++k) {
        o += __shfl(res, k) * Ws[k * 64 + lane];   // stride-1 across lanes: conflict-free
    }
    y[idx] = o;
}

extern "C" void kernel_launch(void* const* d_in, const int* in_sizes, int n_in,
                              void* d_out, int out_size, void* d_ws, size_t ws_size,
                              hipStream_t stream) {
    const float* x  = (const float*)d_in[0];
    const int*   ei = (const int*)d_in[1];   // [2, E] row-major: src then dst
    const float* W  = (const float*)d_in[2];
    const float* b  = (const float*)d_in[3];
    float* out = (float*)d_out;

    const int N = in_sizes[0] / 64;
    const int E = in_sizes[1] / 2;
    const float delta = (float)(5.27 / 2.0);

    // Workspace layout (fp16 buffers have N+1 rows; row N is the zero row).
    char* p = (char*)d_ws;
    __half* zh   = (__half*)p;  p += (size_t)(N + 1) * 64 * sizeof(__half);
    __half* z1h  = (__half*)p;  p += (size_t)(N + 1) * 64 * sizeof(__half);
    __half* x1h  = (__half*)p;  p += (size_t)N * 64 * sizeof(__half);
    int*   col   = (int*)p;     p += (size_t)E * sizeof(int);
    float* dinv  = (float*)p;   p += (size_t)N * sizeof(float);
    int*   counts= (int*)p;     p += (size_t)N * sizeof(int);
    int*   rowp  = (int*)p;     p += (size_t)(N + 4) * sizeof(int);
    int*   cursor= (int*)p;     p += (size_t)N * sizeof(int);
    int*   bsums = (int*)p;     p += 512 * sizeof(int);

    hipMemsetAsync(counts, 0, (size_t)N * sizeof(int), stream);

    int grid_e = (E + TPB - 1) / TPB;
    int grid_n = (N + (TPB / 64) - 1) / (TPB / 64);
    int nb_scan = (N + SCAN_CHUNK - 1) / SCAN_CHUNK;   // 98 for N=100000
    int grid_c = ((N + 1) * 64 + TPB - 1) / TPB;

    count_kernel<<<grid_e, TPB, 0, stream>>>(ei + E, counts, E);
    scan_partials<<<nb_scan, SCAN_T, 0, stream>>>(counts, bsums, N);
    scan_bsums<<<1, 512, 0, stream>>>(bsums, nb_scan, rowp, N, E);
    scan_emit<<<nb_scan, SCAN_T, 0, stream>>>(counts, bsums, rowp, cursor, dinv, N);
    cast_z<<<grid_c, TPB, 0, stream>>>(x, dinv, zh, z1h, N);
    fill_kernel<<<grid_e, TPB, 0, stream>>>(ei, ei + E, cursor, col, E);

    // Step 1: x/zh -> x1h,z1h
    spmm1_kernel<<<grid_n, TPB, 0, stream>>>(x, zh, x1h, z1h, rowp, col, dinv, N, delta);
    // Step 2 + linear, fused: x1h/z1h -> out
    spmm2_gemm_kernel<<<grid_n, TPB, 0, stream>>>(x1h, z1h, out, rowp, col, dinv, W, b, N, delta);
}